// Round 1
// baseline (355.885 us; speedup 1.0000x reference)
//
#include <hip/hip_runtime.h>

typedef __bf16 bf16;
typedef __bf16 bf16x8 __attribute__((ext_vector_type(8)));
typedef __bf16 bf16x4 __attribute__((ext_vector_type(4)));
typedef float f32x4 __attribute__((ext_vector_type(4)));

static constexpr int Hh = 8;    // query heads
static constexpr int Dd = 256;  // head dim
static constexpr int Ss = 2048; // seq len
static constexpr int Cc = 2048; // hidden

typedef const __attribute__((address_space(1))) unsigned int as1_u32;
typedef __attribute__((address_space(3))) unsigned int as3_u32;

// async global->LDS, 16B per lane; lds dest is wave-uniform base + lane*16
__device__ __forceinline__ void gl_lds16(const void* g, void* l) {
  __builtin_amdgcn_global_load_lds((as1_u32*)(unsigned long long)g,
                                   (as3_u32*)(unsigned int)(unsigned long long)l,
                                   16, 0, 0);
}

__device__ __forceinline__ f32x4 mfma16(bf16x8 a, bf16x8 b, f32x4 c) {
  return __builtin_amdgcn_mfma_f32_16x16x32_bf16(a, b, c, 0, 0, 0);
}

// ---------------- elementwise f32 -> bf16 ----------------
__global__ __launch_bounds__(256) void cvt_w(const float* __restrict__ in,
                                             bf16* __restrict__ out, int n) {
  int i = (blockIdx.x * 256 + threadIdx.x) * 4;
  if (i >= n) return;
  const float4 v = *(const float4*)(in + i);
  bf16x4 o;
  o[0] = (bf16)v.x; o[1] = (bf16)v.y; o[2] = (bf16)v.z; o[3] = (bf16)v.w;
  *(bf16x4*)(out + i) = o;
}

// ---------------- [B][R][S] f32 -> [B][S][R] bf16 ----------------
__global__ __launch_bounds__(256) void transpose_cvt(const float* __restrict__ in,
                                                     bf16* __restrict__ out,
                                                     int R, int S) {
  __shared__ float t[32][33];
  const int b = blockIdx.z;
  const long base = (long)b * R * S;
  const int s0 = blockIdx.x * 32, r0 = blockIdx.y * 32;
  const int tx = threadIdx.x, ty = threadIdx.y;
#pragma unroll
  for (int i = 0; i < 32; i += 8)
    t[ty + i][tx] = in[base + (long)(r0 + ty + i) * S + s0 + tx];
  __syncthreads();
#pragma unroll
  for (int i = 0; i < 32; i += 8)
    out[base + (long)(s0 + ty + i) * R + r0 + tx] = (bf16)t[tx][ty + i];
}

// ---------------- RoPE + transpose: [B][nH*256][S] -> [B][nH][S][256] -------
// sint/cost: [B][S][128] bf16 (pre-transposed)
__global__ __launch_bounds__(256) void rope_transpose(
    const bf16* __restrict__ xin, const bf16* __restrict__ sint,
    const bf16* __restrict__ cost, bf16* __restrict__ xout, int nH) {
  __shared__ __align__(16) bf16 ti[32][264];  // [s][d], padded
  const int b = blockIdx.z, h = blockIdx.y, s0 = blockIdx.x * 32;
  const int tx = threadIdx.x, ty = threadIdx.y;
  const bf16* src = xin + ((long)(b * nH + h) * Dd) * Ss + s0;
#pragma unroll
  for (int i = 0; i < 32; ++i) {
    int d = ty + i * 8;
    ti[tx][d] = src[(long)d * Ss + tx];
  }
  __syncthreads();
  const int t = ty * 32 + tx;
  const int s = t >> 3;
  const int dpart = t & 7;
  const bf16* sp = sint + ((long)b * Ss + s0 + s) * 128;
  const bf16* cp = cost + ((long)b * Ss + s0 + s) * 128;
  bf16* dst = xout + (((long)(b * nH + h)) * Ss + s0 + s) * Dd;
#pragma unroll
  for (int i = 0; i < 4; ++i) {
    int d0 = dpart * 8 + i * 64;
    int dh = d0 & 127;
    bf16x8 a = *(const bf16x8*)&ti[s][d0];
    bf16x8 p = *(const bf16x8*)&ti[s][(d0 < 128) ? d0 + 128 : d0 - 128];
    bf16x8 sn = *(const bf16x8*)&sp[dh];
    bf16x8 cs = *(const bf16x8*)&cp[dh];
    bf16x8 o;
#pragma unroll
    for (int j = 0; j < 8; ++j) {
      float av = (float)a[j], pv = (float)p[j];
      float c = (float)cs[j], sv = (float)sn[j];
      float val = (d0 < 128) ? (av * c - pv * sv) : (av * c + pv * sv);
      o[j] = (bf16)val;
    }
    *(bf16x8*)&dst[d0] = o;
  }
}

// ---------------- GEMM: C[z][o][s] = sum_c A[o][c] * Bt[z][s][c] -----------
// A: [M][K] bf16, Bt: per-batch [N][K] bf16. Out bf16 (Cb) or f32 (Cf).
__global__ __launch_bounds__(256, 2) void gemm_bt(
    const bf16* __restrict__ A, const bf16* __restrict__ Bt,
    bf16* __restrict__ Cb, float* __restrict__ Cf, int M, int N, int K,
    long sBt, long sC) {
  __shared__ __align__(16) bf16 lA[128 * 32];
  __shared__ __align__(16) bf16 lB[128 * 32];
  const int tid = threadIdx.x;
  const int wid = tid >> 6, lane = tid & 63;
  const int g = lane >> 4, r = lane & 15;
  const int wr = wid >> 1, wc = wid & 1;
  const int mt = blockIdx.y * 128, nt = blockIdx.x * 128;
  const int z = blockIdx.z;
  const bf16* Bz = Bt + (long)z * sBt;

  const f32x4 zf = {0.f, 0.f, 0.f, 0.f};
  f32x4 acc[4][4];
#pragma unroll
  for (int m = 0; m < 4; ++m)
#pragma unroll
    for (int n = 0; n < 4; ++n) acc[m][n] = zf;

  for (int kt = 0; kt < K; kt += 32) {
#pragma unroll
    for (int it = 0; it < 2; ++it) {
      int off = it * 4096 + tid * 16;   // byte offset in 8KB tile
      int row = off >> 6;               // 64B per row of 32 bf16
      int cc = (off >> 4) & 3;
      gl_lds16((const char*)(A + (long)(mt + row) * K + kt) + cc * 16,
               (char*)lA + it * 4096 + wid * 1024);
      gl_lds16((const char*)(Bz + (long)(nt + row) * K + kt) + cc * 16,
               (char*)lB + it * 4096 + wid * 1024);
    }
    __syncthreads();
    bf16x8 af[4], bfv[4];
#pragma unroll
    for (int m = 0; m < 4; ++m)
      af[m] = *(const bf16x8*)&lA[(wr * 64 + m * 16 + r) * 32 + g * 8];
#pragma unroll
    for (int n = 0; n < 4; ++n)
      bfv[n] = *(const bf16x8*)&lB[(wc * 64 + n * 16 + r) * 32 + g * 8];
#pragma unroll
    for (int m = 0; m < 4; ++m)
#pragma unroll
      for (int n = 0; n < 4; ++n)
        acc[m][n] = mfma16(af[m], bfv[n], acc[m][n]);
    __syncthreads();
  }

#pragma unroll
  for (int m = 0; m < 4; ++m)
#pragma unroll
    for (int n = 0; n < 4; ++n)
#pragma unroll
      for (int e = 0; e < 4; ++e) {
        int orow = mt + wr * 64 + m * 16 + g * 4 + e;
        int col = nt + wc * 64 + n * 16 + r;
        long idx = (long)z * sC + (long)orow * N + col;
        if (Cf) Cf[idx] = acc[m][n][e];
        else Cb[idx] = (bf16)acc[m][n][e];
      }
}

// ---------------- flash attention -----------------------------------------
// qr: [B][H][S][256], kr: [B][S][256], vv: [B][256][S], mask: [B][1][S][S]
// aout: [B][S][H*256]
__global__ __launch_bounds__(256, 2) void attn_kernel(
    const bf16* __restrict__ qr, const bf16* __restrict__ kr,
    const bf16* __restrict__ vv, const float* __restrict__ mask,
    bf16* __restrict__ aout) {
  __shared__ __align__(16) bf16 lK[64 * 256];   // [ks][d], XOR-swizzled 16B chunks
  __shared__ __align__(16) bf16 lV[256 * 64];   // [d][ks], XOR-swizzled
  __shared__ __align__(16) bf16 lP[4][16 * 72]; // per-wave P, padded rows
  const int b = blockIdx.z, h = blockIdx.y;
  const int q0 = blockIdx.x * 64;
  const int tid = threadIdx.x;
  const int wid = tid >> 6, lane = tid & 63;
  const int g = lane >> 4, r = lane & 15;
  const int qw = q0 + wid * 16;

  bf16x8 qf[8];
  const bf16* qp = qr + (((long)(b * Hh + h)) * Ss + qw + r) * Dd;
#pragma unroll
  for (int kk = 0; kk < 8; ++kk) qf[kk] = *(const bf16x8*)&qp[kk * 32 + g * 8];

  const f32x4 zf = {0.f, 0.f, 0.f, 0.f};
  f32x4 oacc[16];
#pragma unroll
  for (int i = 0; i < 16; ++i) oacc[i] = zf;
  float mrun[4] = {-3e38f, -3e38f, -3e38f, -3e38f};
  float lrun[4] = {0.f, 0.f, 0.f, 0.f};

  const char* kb = (const char*)(kr + (long)b * Ss * Dd);
  const char* vb = (const char*)(vv + (long)b * Dd * Ss);
  const float* mb = mask + (long)b * Ss * Ss;

  for (int kt = 0; kt < Ss; kt += 64) {
    // stage K tile [64][256]: linear LDS dest + inverse-swizzled source
    const char* gK = kb + (long)kt * (Dd * 2);
#pragma unroll
    for (int it = 0; it < 8; ++it) {
      int off = it * 4096 + tid * 16;
      int row = off >> 9;               // 512B rows
      int c = (off >> 4) & 31;
      int csw = c ^ (row & 7);
      gl_lds16(gK + row * 512 + csw * 16, (char*)lK + it * 4096 + wid * 1024);
    }
    // stage V tile [256][64]
#pragma unroll
    for (int it = 0; it < 8; ++it) {
      int off = it * 4096 + tid * 16;
      int row = off >> 7;               // 128B rows
      int c = (off >> 4) & 7;
      int csw = c ^ (row & 7);
      gl_lds16(vb + (long)row * (Ss * 2) + kt * 2 + csw * 16,
               (char*)lV + it * 4096 + wid * 1024);
    }
    __syncthreads();

    // QK^T: S[q][ks] for this wave's 16 q-rows x 64 ks
    f32x4 sacc[4] = {zf, zf, zf, zf};
#pragma unroll
    for (int kk = 0; kk < 8; ++kk) {
#pragma unroll
      for (int n = 0; n < 4; ++n) {
        int row = n * 16 + r;
        int csw = (kk * 4 + g) ^ (row & 7);
        bf16x8 kf = *(const bf16x8*)((const char*)lK + row * 512 + csw * 16);
        sacc[n] = mfma16(qf[kk], kf, sacc[n]);
      }
    }

    // scale + mask + online softmax (row = qw + g*4 + e, col = kt + n*16 + r)
#pragma unroll
    for (int e = 0; e < 4; ++e) {
      const int q = qw + g * 4 + e;
      const float* mrow = mb + (long)q * Ss + kt;
      float mx = -3e38f;
#pragma unroll
      for (int n = 0; n < 4; ++n) {
        float x = sacc[n][e] * 0.0625f + mrow[n * 16 + r];
        sacc[n][e] = x;
        mx = fmaxf(mx, x);
      }
      mx = fmaxf(mx, __shfl_xor(mx, 1, 64));
      mx = fmaxf(mx, __shfl_xor(mx, 2, 64));
      mx = fmaxf(mx, __shfl_xor(mx, 4, 64));
      mx = fmaxf(mx, __shfl_xor(mx, 8, 64));
      float mnew = fmaxf(mrun[e], mx);
      float al = __expf(mrun[e] - mnew);
      mrun[e] = mnew;
      float rs = 0.f;
#pragma unroll
      for (int n = 0; n < 4; ++n) {
        float p = __expf(sacc[n][e] - mnew);
        rs += p;
        lP[wid][(g * 4 + e) * 72 + n * 16 + r] = (bf16)p;
      }
      rs += __shfl_xor(rs, 1, 64);
      rs += __shfl_xor(rs, 2, 64);
      rs += __shfl_xor(rs, 4, 64);
      rs += __shfl_xor(rs, 8, 64);
      lrun[e] = lrun[e] * al + rs;
#pragma unroll
      for (int nf = 0; nf < 16; ++nf) oacc[nf][e] *= al;
    }

    // PV: out[q][d] += P[q][ks] * V[d][ks]
#pragma unroll
    for (int kk = 0; kk < 2; ++kk) {
      bf16x8 pf = *(const bf16x8*)&lP[wid][r * 72 + kk * 32 + g * 8];
#pragma unroll
      for (int nf = 0; nf < 16; ++nf) {
        int row = nf * 16 + r;
        int csw = (kk * 4 + g) ^ (row & 7);
        bf16x8 vf = *(const bf16x8*)((const char*)lV + row * 128 + csw * 16);
        oacc[nf] = mfma16(pf, vf, oacc[nf]);
      }
    }
    __syncthreads();
  }

  float inv[4];
#pragma unroll
  for (int e = 0; e < 4; ++e) inv[e] = 1.f / lrun[e];
#pragma unroll
  for (int nf = 0; nf < 16; ++nf)
#pragma unroll
    for (int e = 0; e < 4; ++e) {
      int q = qw + g * 4 + e;
      aout[((long)b * Ss + q) * (Hh * Dd) + h * Dd + nf * 16 + r] =
          (bf16)(oacc[nf][e] * inv[e]);
    }
}

// ---------------- launcher -------------------------------------------------
extern "C" void kernel_launch(void* const* d_in, const int* in_sizes, int n_in,
                              void* d_out, int out_size, void* d_ws,
                              size_t ws_size, hipStream_t stream) {
  const float* Xq = (const float*)d_in[0];
  const float* Xkv = (const float*)d_in[1];
  const float* sin_q = (const float*)d_in[2];
  const float* cos_q = (const float*)d_in[3];
  const float* sin_k = (const float*)d_in[4];
  const float* cos_k = (const float*)d_in[5];
  const float* mask = (const float*)d_in[6];
  const float* Wq = (const float*)d_in[7];
  const float* Wk = (const float*)d_in[8];
  const float* Wv = (const float*)d_in[9];
  const float* Wo = (const float*)d_in[10];
  float* out = (float*)d_out;

  char* ws = (char*)d_ws;
  const size_t MB = 1u << 20;
  bf16* Wq_bf = (bf16*)(ws + 0 * MB);
  bf16* Wo_bf = (bf16*)(ws + 8 * MB);
  bf16* Wk_bf = (bf16*)(ws + 16 * MB);
  bf16* Wv_bf = (bf16*)(ws + 17 * MB);
  bf16* sin_qt = (bf16*)(ws + 18 * MB);
  bf16* cos_qt = (bf16*)(ws + 19 * MB);
  bf16* sin_kt = (bf16*)(ws + 20 * MB);
  bf16* cos_kt = (bf16*)(ws + 21 * MB);
  bf16* Xtq = (bf16*)(ws + 22 * MB);   // reused as qr after GEMM-Q
  bf16* Xtkv = (bf16*)(ws + 38 * MB);  // reused as kr after GEMM-K/V
  bf16* q_tmp = (bf16*)(ws + 54 * MB); // reused as attn out after rope_q
  bf16* k_tmp = (bf16*)(ws + 70 * MB);
  bf16* v_bf = (bf16*)(ws + 72 * MB);
  bf16* qr = (bf16*)(ws + 22 * MB);
  bf16* kr = (bf16*)(ws + 38 * MB);
  bf16* attnb = (bf16*)(ws + 54 * MB);

  dim3 b256(256), b32x8(32, 8);

  // weight converts
  cvt_w<<<4096, b256, 0, stream>>>(Wq, Wq_bf, Cc * Cc);
  cvt_w<<<4096, b256, 0, stream>>>(Wo, Wo_bf, Cc * Cc);
  cvt_w<<<512, b256, 0, stream>>>(Wk, Wk_bf, Dd * Cc);
  cvt_w<<<512, b256, 0, stream>>>(Wv, Wv_bf, Dd * Cc);

  // activations / sin-cos transposed to [S][*] bf16
  transpose_cvt<<<dim3(64, 64, 2), b32x8, 0, stream>>>(Xq, Xtq, Cc, Ss);
  transpose_cvt<<<dim3(64, 64, 2), b32x8, 0, stream>>>(Xkv, Xtkv, Cc, Ss);
  transpose_cvt<<<dim3(64, 4, 2), b32x8, 0, stream>>>(sin_q, sin_qt, 128, Ss);
  transpose_cvt<<<dim3(64, 4, 2), b32x8, 0, stream>>>(cos_q, cos_qt, 128, Ss);
  transpose_cvt<<<dim3(64, 4, 2), b32x8, 0, stream>>>(sin_k, sin_kt, 128, Ss);
  transpose_cvt<<<dim3(64, 4, 2), b32x8, 0, stream>>>(cos_k, cos_kt, 128, Ss);

  // projections
  gemm_bt<<<dim3(16, 16, 2), b256, 0, stream>>>(
      Wq_bf, Xtq, q_tmp, nullptr, Cc, Ss, Cc, (long)Ss * Cc, (long)Cc * Ss);
  gemm_bt<<<dim3(16, 2, 2), b256, 0, stream>>>(
      Wk_bf, Xtkv, k_tmp, nullptr, Dd, Ss, Cc, (long)Ss * Cc, (long)Dd * Ss);
  gemm_bt<<<dim3(16, 2, 2), b256, 0, stream>>>(
      Wv_bf, Xtkv, v_bf, nullptr, Dd, Ss, Cc, (long)Ss * Cc, (long)Dd * Ss);

  // RoPE + layout change
  rope_transpose<<<dim3(64, 8, 2), b32x8, 0, stream>>>(q_tmp, sin_qt, cos_qt,
                                                       qr, Hh);
  rope_transpose<<<dim3(64, 1, 2), b32x8, 0, stream>>>(k_tmp, sin_kt, cos_kt,
                                                       kr, 1);

  // attention
  attn_kernel<<<dim3(32, 8, 2), b256, 0, stream>>>(qr, kr, v_bf, mask, attnb);

  // output projection (f32 out)
  gemm_bt<<<dim3(16, 16, 2), b256, 0, stream>>>(
      Wo_bf, attnb, nullptr, out, Cc, Ss, Cc, (long)Ss * Cc, (long)Cc * Ss);
}

// Round 2
// 341.311 us; speedup vs baseline: 1.0427x; 1.0427x over previous
//
#include <hip/hip_runtime.h>

typedef __bf16 bf16;
typedef __bf16 bf16x8 __attribute__((ext_vector_type(8)));
typedef __bf16 bf16x4 __attribute__((ext_vector_type(4)));
typedef float f32x4 __attribute__((ext_vector_type(4)));

static constexpr int Hh = 8;    // query heads
static constexpr int Dd = 256;  // head dim
static constexpr int Ss = 2048; // seq len
static constexpr int Cc = 2048; // hidden

typedef const __attribute__((address_space(1))) unsigned int as1_u32;
typedef __attribute__((address_space(3))) unsigned int as3_u32;

// async global->LDS, 16B per lane; lds dest is wave-uniform base + lane*16
__device__ __forceinline__ void gl_lds16(const void* g, void* l) {
  __builtin_amdgcn_global_load_lds((as1_u32*)(unsigned long long)g,
                                   (as3_u32*)(unsigned int)(unsigned long long)l,
                                   16, 0, 0);
}

__device__ __forceinline__ f32x4 mfma16(bf16x8 a, bf16x8 b, f32x4 c) {
  return __builtin_amdgcn_mfma_f32_16x16x32_bf16(a, b, c, 0, 0, 0);
}

// ---------------- elementwise f32 -> bf16 ----------------
__global__ __launch_bounds__(256) void cvt_w(const float* __restrict__ in,
                                             bf16* __restrict__ out, int n) {
  int i = (blockIdx.x * 256 + threadIdx.x) * 4;
  if (i >= n) return;
  const float4 v = *(const float4*)(in + i);
  bf16x4 o;
  o[0] = (bf16)v.x; o[1] = (bf16)v.y; o[2] = (bf16)v.z; o[3] = (bf16)v.w;
  *(bf16x4*)(out + i) = o;
}

// ---------------- [B][R][S] f32 -> [B][S][R] bf16 ----------------
__global__ __launch_bounds__(256) void transpose_cvt(const float* __restrict__ in,
                                                     bf16* __restrict__ out,
                                                     int R, int S) {
  __shared__ float t[32][33];
  const int b = blockIdx.z;
  const long base = (long)b * R * S;
  const int s0 = blockIdx.x * 32, r0 = blockIdx.y * 32;
  const int tx = threadIdx.x, ty = threadIdx.y;
#pragma unroll
  for (int i = 0; i < 32; i += 8)
    t[ty + i][tx] = in[base + (long)(r0 + ty + i) * S + s0 + tx];
  __syncthreads();
#pragma unroll
  for (int i = 0; i < 32; i += 8)
    out[base + (long)(s0 + ty + i) * R + r0 + tx] = (bf16)t[tx][ty + i];
}

// ---------------- RoPE + transpose: [B][nH*256][S] -> [B][nH][S][256] -------
// sint/cost: [B][S][128] bf16 (pre-transposed)
__global__ __launch_bounds__(256) void rope_transpose(
    const bf16* __restrict__ xin, const bf16* __restrict__ sint,
    const bf16* __restrict__ cost, bf16* __restrict__ xout, int nH) {
  __shared__ __align__(16) bf16 ti[32][264];  // [s][d], padded
  const int b = blockIdx.z, h = blockIdx.y, s0 = blockIdx.x * 32;
  const int tx = threadIdx.x, ty = threadIdx.y;
  const bf16* src = xin + ((long)(b * nH + h) * Dd) * Ss + s0;
#pragma unroll
  for (int i = 0; i < 32; ++i) {
    int d = ty + i * 8;
    ti[tx][d] = src[(long)d * Ss + tx];
  }
  __syncthreads();
  const int t = ty * 32 + tx;
  const int s = t >> 3;
  const int dpart = t & 7;
  const bf16* sp = sint + ((long)b * Ss + s0 + s) * 128;
  const bf16* cp = cost + ((long)b * Ss + s0 + s) * 128;
  bf16* dst = xout + (((long)(b * nH + h)) * Ss + s0 + s) * Dd;
#pragma unroll
  for (int i = 0; i < 4; ++i) {
    int d0 = dpart * 8 + i * 64;
    int dh = d0 & 127;
    bf16x8 a = *(const bf16x8*)&ti[s][d0];
    bf16x8 p = *(const bf16x8*)&ti[s][(d0 < 128) ? d0 + 128 : d0 - 128];
    bf16x8 sn = *(const bf16x8*)&sp[dh];
    bf16x8 cs = *(const bf16x8*)&cp[dh];
    bf16x8 o;
#pragma unroll
    for (int j = 0; j < 8; ++j) {
      float av = (float)a[j], pv = (float)p[j];
      float c = (float)cs[j], sv = (float)sn[j];
      float val = (d0 < 128) ? (av * c - pv * sv) : (av * c + pv * sv);
      o[j] = (bf16)val;
    }
    *(bf16x8*)&dst[d0] = o;
  }
}

// ---------------- GEMM: C[z][o][s] = sum_c A[o][c] * Bt[z][s][c] -----------
// A: [M][K] bf16, Bt: per-batch [N][K] bf16. Out bf16 (Cb) or f32 (Cf).
// 2-phase pipeline: double-buffered LDS, stage(t+1) before compute(t),
// single barrier per K-step (T3 minimal recipe).
__global__ __launch_bounds__(256, 2) void gemm_bt(
    const bf16* __restrict__ A, const bf16* __restrict__ Bt,
    bf16* __restrict__ Cb, float* __restrict__ Cf, int M, int N, int K,
    long sBt, long sC) {
  __shared__ __align__(16) bf16 lA[2][128 * 32];
  __shared__ __align__(16) bf16 lB[2][128 * 32];
  const int tid = threadIdx.x;
  const int wid = tid >> 6, lane = tid & 63;
  const int g = lane >> 4, r = lane & 15;
  const int wr = wid >> 1, wc = wid & 1;
  const int mt = blockIdx.y * 128, nt = blockIdx.x * 128;
  const int z = blockIdx.z;
  const bf16* Bz = Bt + (long)z * sBt;

  auto stage = [&](int buf, int kt) {
#pragma unroll
    for (int it = 0; it < 2; ++it) {
      int off = it * 4096 + tid * 16;   // byte offset in 8KB tile
      int row = off >> 6;               // 64B per row of 32 bf16
      int cc = (off >> 4) & 3;
      gl_lds16((const char*)(A + (long)(mt + row) * K + kt) + cc * 16,
               (char*)lA[buf] + it * 4096 + wid * 1024);
      gl_lds16((const char*)(Bz + (long)(nt + row) * K + kt) + cc * 16,
               (char*)lB[buf] + it * 4096 + wid * 1024);
    }
  };

  const f32x4 zf = {0.f, 0.f, 0.f, 0.f};
  f32x4 acc[4][4];
#pragma unroll
  for (int m = 0; m < 4; ++m)
#pragma unroll
    for (int n = 0; n < 4; ++n) acc[m][n] = zf;

  stage(0, 0);
  __syncthreads();
  int cur = 0;
  for (int kt = 0; kt < K; kt += 32) {
    if (kt + 32 < K) stage(cur ^ 1, kt + 32);
    bf16x8 af[4], bfv[4];
#pragma unroll
    for (int m = 0; m < 4; ++m)
      af[m] = *(const bf16x8*)&lA[cur][(wr * 64 + m * 16 + r) * 32 + g * 8];
#pragma unroll
    for (int n = 0; n < 4; ++n)
      bfv[n] = *(const bf16x8*)&lB[cur][(wc * 64 + n * 16 + r) * 32 + g * 8];
#pragma unroll
    for (int m = 0; m < 4; ++m)
#pragma unroll
      for (int n = 0; n < 4; ++n)
        acc[m][n] = mfma16(af[m], bfv[n], acc[m][n]);
    __syncthreads();
    cur ^= 1;
  }

#pragma unroll
  for (int m = 0; m < 4; ++m)
#pragma unroll
    for (int n = 0; n < 4; ++n)
#pragma unroll
      for (int e = 0; e < 4; ++e) {
        int orow = mt + wr * 64 + m * 16 + g * 4 + e;
        int col = nt + wc * 64 + n * 16 + r;
        long idx = (long)z * sC + (long)orow * N + col;
        if (Cf) Cf[idx] = acc[m][n][e];
        else Cb[idx] = (bf16)acc[m][n][e];
      }
}

// ---------------- flash attention (GQA-shared, 8 waves, 2-phase) -----------
// qr: [B][H][S][256], kr: [B][S][256], vv: [B][256][S], mask: [B][1][S][S]
// aout: [B][S][H*256]
// Block = 512 threads (8 waves). Wave w handles head w, the SAME 16 q-rows.
// All 8 heads share the staged K/V tiles (HKV=1). K/V double-buffered;
// stage(t+1) issued before compute(t); one barrier per tile.
__global__ __launch_bounds__(512, 2) void attn_kernel(
    const bf16* __restrict__ qr, const bf16* __restrict__ kr,
    const bf16* __restrict__ vv, const float* __restrict__ mask,
    bf16* __restrict__ aout) {
  __shared__ __align__(16) bf16 lK[2][64 * 256];   // [ks][d], XOR-swizzled 16B chunks
  __shared__ __align__(16) bf16 lV[2][256 * 64];   // [d][ks], XOR-swizzled
  __shared__ __align__(16) bf16 lP[8][16 * 72];    // per-wave P, padded rows
  const int b = blockIdx.y;
  const int q0 = blockIdx.x * 16;
  const int tid = threadIdx.x;
  const int wid = tid >> 6, lane = tid & 63;
  const int g = lane >> 4, r = lane & 15;
  const int h = wid;  // head = wave id

  bf16x8 qf[8];
  const bf16* qp = qr + (((long)(b * Hh + h)) * Ss + q0 + r) * Dd;
#pragma unroll
  for (int kk = 0; kk < 8; ++kk) qf[kk] = *(const bf16x8*)&qp[kk * 32 + g * 8];

  const f32x4 zf = {0.f, 0.f, 0.f, 0.f};
  f32x4 oacc[16];
#pragma unroll
  for (int i = 0; i < 16; ++i) oacc[i] = zf;
  float mrun[4] = {-3e38f, -3e38f, -3e38f, -3e38f};
  float lrun[4] = {0.f, 0.f, 0.f, 0.f};

  const char* kb = (const char*)(kr + (long)b * Ss * Dd);
  const char* vb = (const char*)(vv + (long)b * Dd * Ss);
  const float* mb = mask + (long)b * Ss * Ss;

  // stage K [64][256] + V [256][64] tiles: linear LDS dest, inverse-swizzled src
  auto stage = [&](int buf, int kt) {
    const char* gK = kb + (long)kt * (Dd * 2);
#pragma unroll
    for (int it = 0; it < 4; ++it) {
      int off = it * 8192 + tid * 16;
      int row = off >> 9;               // 512B rows
      int c = (off >> 4) & 31;
      int csw = c ^ (row & 7);
      gl_lds16(gK + row * 512 + csw * 16,
               (char*)lK[buf] + it * 8192 + wid * 1024);
    }
#pragma unroll
    for (int it = 0; it < 4; ++it) {
      int off = it * 8192 + tid * 16;
      int row = off >> 7;               // 128B rows
      int c = (off >> 4) & 7;
      int csw = c ^ (row & 7);
      gl_lds16(vb + (long)row * (Ss * 2) + (long)kt * 2 + csw * 16,
               (char*)lV[buf] + it * 8192 + wid * 1024);
    }
  };

  stage(0, 0);
  __syncthreads();
  int cur = 0;

  for (int kt = 0; kt < Ss; kt += 64) {
    if (kt + 64 < Ss) stage(cur ^ 1, kt + 64);
    const char* lKc = (const char*)lK[cur];
    const char* lVc = (const char*)lV[cur];

    // QK^T: S[q][ks] for this wave's 16 q-rows x 64 ks
    f32x4 sacc[4] = {zf, zf, zf, zf};
    __builtin_amdgcn_s_setprio(1);
#pragma unroll
    for (int kk = 0; kk < 8; ++kk) {
#pragma unroll
      for (int n = 0; n < 4; ++n) {
        int row = n * 16 + r;
        int csw = (kk * 4 + g) ^ (row & 7);
        bf16x8 kf = *(const bf16x8*)(lKc + row * 512 + csw * 16);
        sacc[n] = mfma16(qf[kk], kf, sacc[n]);
      }
    }
    __builtin_amdgcn_s_setprio(0);

    // scale + mask + online softmax (row = q0 + g*4 + e, col = kt + n*16 + r)
#pragma unroll
    for (int e = 0; e < 4; ++e) {
      const int q = q0 + g * 4 + e;
      const float* mrow = mb + (long)q * Ss + kt;
      float mx = -3e38f;
#pragma unroll
      for (int n = 0; n < 4; ++n) {
        float x = sacc[n][e] * 0.0625f + mrow[n * 16 + r];
        sacc[n][e] = x;
        mx = fmaxf(mx, x);
      }
      mx = fmaxf(mx, __shfl_xor(mx, 1, 64));
      mx = fmaxf(mx, __shfl_xor(mx, 2, 64));
      mx = fmaxf(mx, __shfl_xor(mx, 4, 64));
      mx = fmaxf(mx, __shfl_xor(mx, 8, 64));
      float mnew = fmaxf(mrun[e], mx);
      float al = __expf(mrun[e] - mnew);
      mrun[e] = mnew;
      float rs = 0.f;
#pragma unroll
      for (int n = 0; n < 4; ++n) {
        float p = __expf(sacc[n][e] - mnew);
        rs += p;
        lP[wid][(g * 4 + e) * 72 + n * 16 + r] = (bf16)p;
      }
      rs += __shfl_xor(rs, 1, 64);
      rs += __shfl_xor(rs, 2, 64);
      rs += __shfl_xor(rs, 4, 64);
      rs += __shfl_xor(rs, 8, 64);
      lrun[e] = lrun[e] * al + rs;
#pragma unroll
      for (int nf = 0; nf < 16; ++nf) oacc[nf][e] *= al;
    }

    // PV: out[q][d] += P[q][ks] * V[d][ks]
    __builtin_amdgcn_s_setprio(1);
#pragma unroll
    for (int kk = 0; kk < 2; ++kk) {
      bf16x8 pf = *(const bf16x8*)&lP[wid][r * 72 + kk * 32 + g * 8];
#pragma unroll
      for (int nf = 0; nf < 16; ++nf) {
        int row = nf * 16 + r;
        int csw = (kk * 4 + g) ^ (row & 7);
        bf16x8 vf = *(const bf16x8*)(lVc + row * 128 + csw * 16);
        oacc[nf] = mfma16(pf, vf, oacc[nf]);
      }
    }
    __builtin_amdgcn_s_setprio(0);

    __syncthreads();
    cur ^= 1;
  }

  float inv[4];
#pragma unroll
  for (int e = 0; e < 4; ++e) inv[e] = 1.f / lrun[e];
#pragma unroll
  for (int nf = 0; nf < 16; ++nf)
#pragma unroll
    for (int e = 0; e < 4; ++e) {
      int q = q0 + g * 4 + e;
      aout[((long)b * Ss + q) * (Hh * Dd) + h * Dd + nf * 16 + r] =
          (bf16)(oacc[nf][e] * inv[e]);
    }
}

// ---------------- launcher -------------------------------------------------
extern "C" void kernel_launch(void* const* d_in, const int* in_sizes, int n_in,
                              void* d_out, int out_size, void* d_ws,
                              size_t ws_size, hipStream_t stream) {
  const float* Xq = (const float*)d_in[0];
  const float* Xkv = (const float*)d_in[1];
  const float* sin_q = (const float*)d_in[2];
  const float* cos_q = (const float*)d_in[3];
  const float* sin_k = (const float*)d_in[4];
  const float* cos_k = (const float*)d_in[5];
  const float* mask = (const float*)d_in[6];
  const float* Wq = (const float*)d_in[7];
  const float* Wk = (const float*)d_in[8];
  const float* Wv = (const float*)d_in[9];
  const float* Wo = (const float*)d_in[10];
  float* out = (float*)d_out;

  char* ws = (char*)d_ws;
  const size_t MB = 1u << 20;
  bf16* Wq_bf = (bf16*)(ws + 0 * MB);
  bf16* Wo_bf = (bf16*)(ws + 8 * MB);
  bf16* Wk_bf = (bf16*)(ws + 16 * MB);
  bf16* Wv_bf = (bf16*)(ws + 17 * MB);
  bf16* sin_qt = (bf16*)(ws + 18 * MB);
  bf16* cos_qt = (bf16*)(ws + 19 * MB);
  bf16* sin_kt = (bf16*)(ws + 20 * MB);
  bf16* cos_kt = (bf16*)(ws + 21 * MB);
  bf16* Xtq = (bf16*)(ws + 22 * MB);   // reused as qr after GEMM-Q
  bf16* Xtkv = (bf16*)(ws + 38 * MB);  // reused as kr after GEMM-K/V
  bf16* q_tmp = (bf16*)(ws + 54 * MB); // reused as attn out after rope_q
  bf16* k_tmp = (bf16*)(ws + 70 * MB);
  bf16* v_bf = (bf16*)(ws + 72 * MB);
  bf16* qr = (bf16*)(ws + 22 * MB);
  bf16* kr = (bf16*)(ws + 38 * MB);
  bf16* attnb = (bf16*)(ws + 54 * MB);

  dim3 b256(256), b32x8(32, 8);

  // weight converts
  cvt_w<<<4096, b256, 0, stream>>>(Wq, Wq_bf, Cc * Cc);
  cvt_w<<<4096, b256, 0, stream>>>(Wo, Wo_bf, Cc * Cc);
  cvt_w<<<512, b256, 0, stream>>>(Wk, Wk_bf, Dd * Cc);
  cvt_w<<<512, b256, 0, stream>>>(Wv, Wv_bf, Dd * Cc);

  // activations / sin-cos transposed to [S][*] bf16
  transpose_cvt<<<dim3(64, 64, 2), b32x8, 0, stream>>>(Xq, Xtq, Cc, Ss);
  transpose_cvt<<<dim3(64, 64, 2), b32x8, 0, stream>>>(Xkv, Xtkv, Cc, Ss);
  transpose_cvt<<<dim3(64, 4, 2), b32x8, 0, stream>>>(sin_q, sin_qt, 128, Ss);
  transpose_cvt<<<dim3(64, 4, 2), b32x8, 0, stream>>>(cos_q, cos_qt, 128, Ss);
  transpose_cvt<<<dim3(64, 4, 2), b32x8, 0, stream>>>(sin_k, sin_kt, 128, Ss);
  transpose_cvt<<<dim3(64, 4, 2), b32x8, 0, stream>>>(cos_k, cos_kt, 128, Ss);

  // projections
  gemm_bt<<<dim3(16, 16, 2), b256, 0, stream>>>(
      Wq_bf, Xtq, q_tmp, nullptr, Cc, Ss, Cc, (long)Ss * Cc, (long)Cc * Ss);
  gemm_bt<<<dim3(16, 2, 2), b256, 0, stream>>>(
      Wk_bf, Xtkv, k_tmp, nullptr, Dd, Ss, Cc, (long)Ss * Cc, (long)Dd * Ss);
  gemm_bt<<<dim3(16, 2, 2), b256, 0, stream>>>(
      Wv_bf, Xtkv, v_bf, nullptr, Dd, Ss, Cc, (long)Ss * Cc, (long)Dd * Ss);

  // RoPE + layout change
  rope_transpose<<<dim3(64, 8, 2), b32x8, 0, stream>>>(q_tmp, sin_qt, cos_qt,
                                                       qr, Hh);
  rope_transpose<<<dim3(64, 1, 2), b32x8, 0, stream>>>(k_tmp, sin_kt, cos_kt,
                                                       kr, 1);

  // attention: 8 waves = 8 heads sharing K/V tiles, 16 q-rows per block
  attn_kernel<<<dim3(128, 2), 512, 0, stream>>>(qr, kr, v_bf, mask, attnb);

  // output projection (f32 out)
  gemm_bt<<<dim3(16, 16, 2), b256, 0, stream>>>(
      Wo_bf, attnb, nullptr, out, Cc, Ss, Cc, (long)Ss * Cc, (long)Cc * Ss);
}

// Round 3
// 298.221 us; speedup vs baseline: 1.1934x; 1.1445x over previous
//
#include <hip/hip_runtime.h>

typedef __bf16 bf16;
typedef __bf16 bf16x8 __attribute__((ext_vector_type(8)));
typedef __bf16 bf16x4 __attribute__((ext_vector_type(4)));
typedef float f32x4 __attribute__((ext_vector_type(4)));

static constexpr int Hh = 8;    // query heads
static constexpr int Dd = 256;  // head dim
static constexpr int Ss = 2048; // seq len
static constexpr int Cc = 2048; // hidden

typedef const __attribute__((address_space(1))) unsigned int as1_u32;
typedef __attribute__((address_space(3))) unsigned int as3_u32;

// async global->LDS, 16B per lane; lds dest is wave-uniform base + lane*16
__device__ __forceinline__ void gl_lds16(const void* g, void* l) {
  __builtin_amdgcn_global_load_lds((as1_u32*)(unsigned long long)g,
                                   (as3_u32*)(unsigned int)(unsigned long long)l,
                                   16, 0, 0);
}

__device__ __forceinline__ f32x4 mfma16(bf16x8 a, bf16x8 b, f32x4 c) {
  return __builtin_amdgcn_mfma_f32_16x16x32_bf16(a, b, c, 0, 0, 0);
}

// ---------------- elementwise f32 -> bf16 ----------------
__global__ __launch_bounds__(256) void cvt_w(const float* __restrict__ in,
                                             bf16* __restrict__ out, int n) {
  int i = (blockIdx.x * 256 + threadIdx.x) * 4;
  if (i >= n) return;
  const float4 v = *(const float4*)(in + i);
  bf16x4 o;
  o[0] = (bf16)v.x; o[1] = (bf16)v.y; o[2] = (bf16)v.z; o[3] = (bf16)v.w;
  *(bf16x4*)(out + i) = o;
}

// ---------------- [B][R][S] f32 -> [B][S][R] bf16 ----------------
__global__ __launch_bounds__(256) void transpose_cvt(const float* __restrict__ in,
                                                     bf16* __restrict__ out,
                                                     int R, int S) {
  __shared__ float t[32][33];
  const int b = blockIdx.z;
  const long base = (long)b * R * S;
  const int s0 = blockIdx.x * 32, r0 = blockIdx.y * 32;
  const int tx = threadIdx.x, ty = threadIdx.y;
#pragma unroll
  for (int i = 0; i < 32; i += 8)
    t[ty + i][tx] = in[base + (long)(r0 + ty + i) * S + s0 + tx];
  __syncthreads();
#pragma unroll
  for (int i = 0; i < 32; i += 8)
    out[base + (long)(s0 + ty + i) * R + r0 + tx] = (bf16)t[tx][ty + i];
}

// ---------------- RoPE + transpose: [B][nH*256][S] -> [B][nH][S][256] -------
// sint/cost: [B][S][128] bf16 (pre-transposed)
__global__ __launch_bounds__(256) void rope_transpose(
    const bf16* __restrict__ xin, const bf16* __restrict__ sint,
    const bf16* __restrict__ cost, bf16* __restrict__ xout, int nH) {
  __shared__ __align__(16) bf16 ti[32][264];  // [s][d], padded
  const int b = blockIdx.z, h = blockIdx.y, s0 = blockIdx.x * 32;
  const int tx = threadIdx.x, ty = threadIdx.y;
  const bf16* src = xin + ((long)(b * nH + h) * Dd) * Ss + s0;
#pragma unroll
  for (int i = 0; i < 32; ++i) {
    int d = ty + i * 8;
    ti[tx][d] = src[(long)d * Ss + tx];
  }
  __syncthreads();
  const int t = ty * 32 + tx;
  const int s = t >> 3;
  const int dpart = t & 7;
  const bf16* sp = sint + ((long)b * Ss + s0 + s) * 128;
  const bf16* cp = cost + ((long)b * Ss + s0 + s) * 128;
  bf16* dst = xout + (((long)(b * nH + h)) * Ss + s0 + s) * Dd;
#pragma unroll
  for (int i = 0; i < 4; ++i) {
    int d0 = dpart * 8 + i * 64;
    int dh = d0 & 127;
    bf16x8 a = *(const bf16x8*)&ti[s][d0];
    bf16x8 p = *(const bf16x8*)&ti[s][(d0 < 128) ? d0 + 128 : d0 - 128];
    bf16x8 sn = *(const bf16x8*)&sp[dh];
    bf16x8 cs = *(const bf16x8*)&cp[dh];
    bf16x8 o;
#pragma unroll
    for (int j = 0; j < 8; ++j) {
      float av = (float)a[j], pv = (float)p[j];
      float c = (float)cs[j], sv = (float)sn[j];
      float val = (d0 < 128) ? (av * c - pv * sv) : (av * c + pv * sv);
      o[j] = (bf16)val;
    }
    *(bf16x8*)&dst[d0] = o;
  }
}

// ---------------- GEMM: C[z][o][s] = sum_c A[o][c] * Bt[z][s][c] -----------
// A: [M][K] bf16, Bt: per-batch [N][K] bf16. Out bf16 (Cb) or f32 (Cf).
// BK=64, XOR-swizzled LDS (chunk ^ row&7), double-buffered, 1 barrier/step.
__global__ __launch_bounds__(256, 2) void gemm_bt(
    const bf16* __restrict__ A, const bf16* __restrict__ Bt,
    bf16* __restrict__ Cb, float* __restrict__ Cf, int M, int N, int K,
    long sBt, long sC) {
  __shared__ __align__(16) bf16 lA[2][128 * 64];
  __shared__ __align__(16) bf16 lB[2][128 * 64];
  const int tid = threadIdx.x;
  const int wid = tid >> 6, lane = tid & 63;
  const int g = lane >> 4, r = lane & 15;
  const int wr = wid >> 1, wc = wid & 1;
  const int mt = blockIdx.y * 128, nt = blockIdx.x * 128;
  const int z = blockIdx.z;
  const bf16* Bz = Bt + (long)z * sBt;

  // stage 16KB tile per matrix: LDS slot (row, c) holds global chunk c^(row&7)
  auto stage = [&](int buf, int kt) {
#pragma unroll
    for (int it = 0; it < 4; ++it) {
      int off = it * 4096 + tid * 16;
      int row = off >> 7;              // 128B rows (64 bf16)
      int c = (off >> 4) & 7;
      int csw = c ^ (row & 7);
      gl_lds16((const char*)(A + (long)(mt + row) * K + kt) + csw * 16,
               (char*)lA[buf] + it * 4096 + wid * 1024);
      gl_lds16((const char*)(Bz + (long)(nt + row) * K + kt) + csw * 16,
               (char*)lB[buf] + it * 4096 + wid * 1024);
    }
  };

  const f32x4 zf = {0.f, 0.f, 0.f, 0.f};
  f32x4 acc[4][4];
#pragma unroll
  for (int m = 0; m < 4; ++m)
#pragma unroll
    for (int n = 0; n < 4; ++n) acc[m][n] = zf;

  stage(0, 0);
  __syncthreads();
  int cur = 0;
  for (int kt = 0; kt < K; kt += 64) {
    if (kt + 64 < K) stage(cur ^ 1, kt + 64);
#pragma unroll
    for (int kk = 0; kk < 2; ++kk) {
      bf16x8 af[4], bfv[4];
#pragma unroll
      for (int m = 0; m < 4; ++m) {
        int row = wr * 64 + m * 16 + r;
        int csw = (kk * 4 + g) ^ (row & 7);
        af[m] = *(const bf16x8*)((const char*)lA[cur] + row * 128 + csw * 16);
      }
#pragma unroll
      for (int n = 0; n < 4; ++n) {
        int row = wc * 64 + n * 16 + r;
        int csw = (kk * 4 + g) ^ (row & 7);
        bfv[n] = *(const bf16x8*)((const char*)lB[cur] + row * 128 + csw * 16);
      }
#pragma unroll
      for (int m = 0; m < 4; ++m)
#pragma unroll
        for (int n = 0; n < 4; ++n)
          acc[m][n] = mfma16(af[m], bfv[n], acc[m][n]);
    }
    __syncthreads();
    cur ^= 1;
  }

#pragma unroll
  for (int m = 0; m < 4; ++m)
#pragma unroll
    for (int n = 0; n < 4; ++n)
#pragma unroll
      for (int e = 0; e < 4; ++e) {
        int orow = mt + wr * 64 + m * 16 + g * 4 + e;
        int col = nt + wc * 64 + n * 16 + r;
        long idx = (long)z * sC + (long)orow * N + col;
        if (Cf) Cf[idx] = acc[m][n][e];
        else Cb[idx] = (bf16)acc[m][n][e];
      }
}

// ---------------- flash attention: swapped QK^T, in-register softmax -------
// qr: [B][H][S][256], kr: [B][S][256], vv: [B][256][S], mask: [B][1][S][S]
// aout: [B][S][H*256]
// 4 waves/block = 4 heads (hg selects which 4); 16 q-rows/block; KVBLK=32.
// Swapped: sacc = mfma(K_frag, Q_frag) -> lane (g,q) holds S[q][16n+4g+e].
// Row-softmax is in-register + 2 shfl. P -> per-wave LDS -> PV B-frag.
// LDS 70.6KB -> 2 blocks/CU; 512 blocks -> 2 resident blocks per CU.
__global__ __launch_bounds__(256, 2) void attn_kernel(
    const bf16* __restrict__ qr, const bf16* __restrict__ kr,
    const bf16* __restrict__ vv, const float* __restrict__ mask,
    bf16* __restrict__ aout) {
  __shared__ __align__(16) bf16 lK[2][32 * 256];  // [ks][d], chunk^(row&7)
  __shared__ __align__(16) bf16 lV[2][256 * 32];  // [d][ks], chunk^((row>>1)&3)
  __shared__ __align__(16) bf16 lP[4][16 * 40];   // per-wave P[q][32+pad]
  const int b = blockIdx.z, hg = blockIdx.y;
  const int q0 = blockIdx.x * 16;
  const int tid = threadIdx.x;
  const int wid = tid >> 6, lane = tid & 63;
  const int g = lane >> 4, q = lane & 15;
  const int h = hg * 4 + wid;

  bf16x8 qf[8];
  const bf16* qp = qr + (((long)(b * Hh + h)) * Ss + q0 + q) * Dd;
#pragma unroll
  for (int kk = 0; kk < 8; ++kk) qf[kk] = *(const bf16x8*)&qp[kk * 32 + g * 8];

  const f32x4 zf = {0.f, 0.f, 0.f, 0.f};
  f32x4 oacc[16];
#pragma unroll
  for (int i = 0; i < 16; ++i) oacc[i] = zf;
  float mrun = -3e38f, lrun = 0.f;

  const char* kb = (const char*)(kr + (long)b * Ss * Dd);
  const char* vb = (const char*)(vv + (long)b * Dd * Ss);
  const float* mb = mask + (long)b * Ss * Ss;

  // stage K [32][256] + V [256][32]; linear LDS dest, inverse-swizzled source
  auto stage = [&](int buf, int kt) {
    const char* gK = kb + (long)kt * 512;
#pragma unroll
    for (int it = 0; it < 4; ++it) {
      int off = it * 4096 + tid * 16;
      int row = off >> 9;               // 512B rows
      int c = (off >> 4) & 31;
      int csw = c ^ (row & 7);
      gl_lds16(gK + row * 512 + csw * 16,
               (char*)lK[buf] + it * 4096 + wid * 1024);
    }
#pragma unroll
    for (int it = 0; it < 4; ++it) {
      int off = it * 4096 + tid * 16;
      int row = off >> 6;               // 64B rows
      int c = (off >> 4) & 3;
      int csw = c ^ ((row >> 1) & 3);
      gl_lds16(vb + (long)row * (Ss * 2) + (long)kt * 2 + csw * 16,
               (char*)lV[buf] + it * 4096 + wid * 1024);
    }
  };

  stage(0, 0);
  __syncthreads();
  int cur = 0;

  for (int kt = 0; kt < Ss; kt += 32) {
    if (kt + 32 < Ss) stage(cur ^ 1, kt + 32);

    // mask prefetch: lane (g,q) needs cols kt+16n+4g..+3 of row q0+q
    const float* mrow = mb + (long)(q0 + q) * Ss + kt;
    const float4 mv0 = *(const float4*)(mrow + 4 * g);
    const float4 mv1 = *(const float4*)(mrow + 16 + 4 * g);

    // QK^T swapped: sacc[n][e] = S[q][ks = 16n + 4g + e]
    f32x4 sacc[2] = {zf, zf};
    __builtin_amdgcn_s_setprio(1);
#pragma unroll
    for (int kk = 0; kk < 8; ++kk) {
#pragma unroll
      for (int n = 0; n < 2; ++n) {
        int row = n * 16 + q;
        int csw = (kk * 4 + g) ^ (row & 7);
        bf16x8 kf = *(const bf16x8*)((const char*)lK[cur] + row * 512 + csw * 16);
        sacc[n] = mfma16(kf, qf[kk], sacc[n]);
      }
    }
    __builtin_amdgcn_s_setprio(0);

    // in-register softmax over this lane's 8 score values
    float x[8];
    x[0] = sacc[0][0] * 0.0625f + mv0.x;
    x[1] = sacc[0][1] * 0.0625f + mv0.y;
    x[2] = sacc[0][2] * 0.0625f + mv0.z;
    x[3] = sacc[0][3] * 0.0625f + mv0.w;
    x[4] = sacc[1][0] * 0.0625f + mv1.x;
    x[5] = sacc[1][1] * 0.0625f + mv1.y;
    x[6] = sacc[1][2] * 0.0625f + mv1.z;
    x[7] = sacc[1][3] * 0.0625f + mv1.w;
    float mx = fmaxf(fmaxf(fmaxf(x[0], x[1]), fmaxf(x[2], x[3])),
                     fmaxf(fmaxf(x[4], x[5]), fmaxf(x[6], x[7])));
    mx = fmaxf(mx, __shfl_xor(mx, 16, 64));
    mx = fmaxf(mx, __shfl_xor(mx, 32, 64));
    // defer-max (T13, THR=8): rescale only when row max grew materially
    if (mx > mrun + 8.0f) {
      float al = __expf(mrun - mx);
      lrun *= al;
#pragma unroll
      for (int nf = 0; nf < 16; ++nf) oacc[nf] *= al;
      mrun = mx;
    }
    float p[8];
    float rs = 0.f;
#pragma unroll
    for (int i = 0; i < 8; ++i) {
      p[i] = __expf(x[i] - mrun);
      rs += p[i];
    }
    rs += __shfl_xor(rs, 16, 64);
    rs += __shfl_xor(rs, 32, 64);
    lrun += rs;

    // P -> per-wave LDS: elems q*40 + 16n + 4g (no barrier: same-wave reuse)
    bf16x4 w0, w1;
#pragma unroll
    for (int e = 0; e < 4; ++e) { w0[e] = (bf16)p[e]; w1[e] = (bf16)p[4 + e]; }
    *(bf16x4*)&lP[wid][q * 40 + 4 * g] = w0;
    *(bf16x4*)&lP[wid][q * 40 + 16 + 4 * g] = w1;

    // PV: O^T[d][q] += V[d][ks] * P[q][ks]
    bf16x8 pf = *(const bf16x8*)&lP[wid][q * 40 + g * 8];
    __builtin_amdgcn_s_setprio(1);
#pragma unroll
    for (int nf = 0; nf < 16; ++nf) {
      int row = nf * 16 + q;
      int csw = g ^ ((row >> 1) & 3);
      bf16x8 vf = *(const bf16x8*)((const char*)lV[cur] + row * 64 + csw * 16);
      oacc[nf] = mfma16(vf, pf, oacc[nf]);
    }
    __builtin_amdgcn_s_setprio(0);

    __syncthreads();
    cur ^= 1;
  }

  const float inv = 1.f / lrun;
  bf16* op = aout + ((long)(b * Ss + q0 + q)) * (Hh * Dd) + h * Dd + g * 4;
#pragma unroll
  for (int nf = 0; nf < 16; ++nf) {
    bf16x4 o4;
#pragma unroll
    for (int e = 0; e < 4; ++e) o4[e] = (bf16)(oacc[nf][e] * inv);
    *(bf16x4*)&op[nf * 16] = o4;
  }
}

// ---------------- launcher -------------------------------------------------
extern "C" void kernel_launch(void* const* d_in, const int* in_sizes, int n_in,
                              void* d_out, int out_size, void* d_ws,
                              size_t ws_size, hipStream_t stream) {
  const float* Xq = (const float*)d_in[0];
  const float* Xkv = (const float*)d_in[1];
  const float* sin_q = (const float*)d_in[2];
  const float* cos_q = (const float*)d_in[3];
  const float* sin_k = (const float*)d_in[4];
  const float* cos_k = (const float*)d_in[5];
  const float* mask = (const float*)d_in[6];
  const float* Wq = (const float*)d_in[7];
  const float* Wk = (const float*)d_in[8];
  const float* Wv = (const float*)d_in[9];
  const float* Wo = (const float*)d_in[10];
  float* out = (float*)d_out;

  char* ws = (char*)d_ws;
  const size_t MB = 1u << 20;
  bf16* Wq_bf = (bf16*)(ws + 0 * MB);
  bf16* Wo_bf = (bf16*)(ws + 8 * MB);
  bf16* Wk_bf = (bf16*)(ws + 16 * MB);
  bf16* Wv_bf = (bf16*)(ws + 17 * MB);
  bf16* sin_qt = (bf16*)(ws + 18 * MB);
  bf16* cos_qt = (bf16*)(ws + 19 * MB);
  bf16* sin_kt = (bf16*)(ws + 20 * MB);
  bf16* cos_kt = (bf16*)(ws + 21 * MB);
  bf16* Xtq = (bf16*)(ws + 22 * MB);   // reused as qr after GEMM-Q
  bf16* Xtkv = (bf16*)(ws + 38 * MB);  // reused as kr after GEMM-K/V
  bf16* q_tmp = (bf16*)(ws + 54 * MB); // reused as attn out after rope_q
  bf16* k_tmp = (bf16*)(ws + 70 * MB);
  bf16* v_bf = (bf16*)(ws + 72 * MB);
  bf16* qr = (bf16*)(ws + 22 * MB);
  bf16* kr = (bf16*)(ws + 38 * MB);
  bf16* attnb = (bf16*)(ws + 54 * MB);

  dim3 b256(256), b32x8(32, 8);

  // weight converts
  cvt_w<<<4096, b256, 0, stream>>>(Wq, Wq_bf, Cc * Cc);
  cvt_w<<<4096, b256, 0, stream>>>(Wo, Wo_bf, Cc * Cc);
  cvt_w<<<512, b256, 0, stream>>>(Wk, Wk_bf, Dd * Cc);
  cvt_w<<<512, b256, 0, stream>>>(Wv, Wv_bf, Dd * Cc);

  // activations / sin-cos transposed to [S][*] bf16
  transpose_cvt<<<dim3(64, 64, 2), b32x8, 0, stream>>>(Xq, Xtq, Cc, Ss);
  transpose_cvt<<<dim3(64, 64, 2), b32x8, 0, stream>>>(Xkv, Xtkv, Cc, Ss);
  transpose_cvt<<<dim3(64, 4, 2), b32x8, 0, stream>>>(sin_q, sin_qt, 128, Ss);
  transpose_cvt<<<dim3(64, 4, 2), b32x8, 0, stream>>>(cos_q, cos_qt, 128, Ss);
  transpose_cvt<<<dim3(64, 4, 2), b32x8, 0, stream>>>(sin_k, sin_kt, 128, Ss);
  transpose_cvt<<<dim3(64, 4, 2), b32x8, 0, stream>>>(cos_k, cos_kt, 128, Ss);

  // projections
  gemm_bt<<<dim3(16, 16, 2), b256, 0, stream>>>(
      Wq_bf, Xtq, q_tmp, nullptr, Cc, Ss, Cc, (long)Ss * Cc, (long)Cc * Ss);
  gemm_bt<<<dim3(16, 2, 2), b256, 0, stream>>>(
      Wk_bf, Xtkv, k_tmp, nullptr, Dd, Ss, Cc, (long)Ss * Cc, (long)Dd * Ss);
  gemm_bt<<<dim3(16, 2, 2), b256, 0, stream>>>(
      Wv_bf, Xtkv, v_bf, nullptr, Dd, Ss, Cc, (long)Ss * Cc, (long)Dd * Ss);

  // RoPE + layout change
  rope_transpose<<<dim3(64, 8, 2), b32x8, 0, stream>>>(q_tmp, sin_qt, cos_qt,
                                                       qr, Hh);
  rope_transpose<<<dim3(64, 1, 2), b32x8, 0, stream>>>(k_tmp, sin_kt, cos_kt,
                                                       kr, 1);

  // attention: 4 waves = 4 heads/block, 16 q-rows, 512 blocks (2/CU)
  attn_kernel<<<dim3(128, 2, 2), b256, 0, stream>>>(qr, kr, v_bf, mask, attnb);

  // output projection (f32 out)
  gemm_bt<<<dim3(16, 16, 2), b256, 0, stream>>>(
      Wo_bf, attnb, nullptr, out, Cc, Ss, Cc, (long)Ss * Cc, (long)Cc * Ss);
}